// Round 1
// baseline (1018.262 us; speedup 1.0000x reference)
//
#include <hip/hip_runtime.h>
#include <stdint.h>

// 25-qubit, 8-layer RY + CNOT-chain circuit. CNOT chains are deferred into a
// GF(2) change-of-basis (sigma); only the 200 RYs touch the 2^25-float state.
// State lives in d_ws (128 MiB, fits L3). Per layer: passB (15 masks, pivots
// bits 0..14, contiguous tiles) + passA (10 masks, pivots 15..24, combo
// gathers). Gates applied in register-resident 5-qubit hypercubes (32
// floats/thread), LDS (128 KiB/block, XOR-swizzled) for repartition.

struct PassArgsB { uint32_t mm[15]; uint32_t ff[15]; uint32_t pf[15]; };
struct PassArgsA { uint32_t mm[10]; uint32_t ff[10]; uint32_t pf[10]; };

__global__ void kprep(const float* __restrict__ theta, float* __restrict__ trig,
                      float* __restrict__ outp)
{
  int t = threadIdx.x;
  if (t == 0) outp[0] = 0.0f;
  if (t < 200) {
    int l = t / 25, b = t % 25;            // b = bit position, qubit w = 24-b
    float th = theta[l * 25 + (24 - b)] * 0.5f;
    trig[2 * t]     = cosf(th);
    trig[2 * t + 1] = sinf(th);
  }
}

// ---------------- passB rounds (15 masks, all within bits 0..14) -----------
template<int R>
__device__ __forceinline__ void doRoundB(float* __restrict__ lds, const PassArgsB& pa,
                                         const float2* __restrict__ cs2, uint32_t bb,
                                         float* __restrict__ state)
{
  const uint32_t t = threadIdx.x;
  uint32_t cumt = 0u;
#pragma unroll
  for (int k = 0; k < 10; ++k) {
    const int d = (R == 0) ? (5 + k) : (R == 1) ? (k < 5 ? k : 5 + k) : k;
    cumt ^= ((t >> k) & 1u) ? pa.mm[d] : 0u;
  }
  float v[32];
  {
    uint32_t la = cumt ^ ((cumt >> 5) & 31u);
    v[0] = lds[la];
#pragma unroll
    for (int k = 1; k < 32; ++k) {
      const int j = __builtin_ctz((unsigned)k);
      const uint32_t m = pa.mm[5 * R + j];
      la ^= m ^ ((m >> 5) & 31u);
      v[k ^ (k >> 1)] = lds[la];
    }
  }
#pragma unroll
  for (int j = 0; j < 5; ++j) {
    const int dim = 5 * R + j;
    const float2 w = cs2[dim];
    const float c = w.x, s = w.y, ns = -s;
    const uint32_t tp = __popc((bb ^ cumt) & pa.ff[dim]) & 1u;
    const uint32_t pf5 = (pa.pf[dim] >> (5 * R)) & 31u;
    uint32_t par32 = 0u;
    par32 ^= (pf5 & 1u)  ? 0xAAAAAAAAu : 0u;
    par32 ^= (pf5 & 2u)  ? 0xCCCCCCCCu : 0u;
    par32 ^= (pf5 & 4u)  ? 0xF0F0F0F0u : 0u;
    par32 ^= (pf5 & 8u)  ? 0xFF00FF00u : 0u;
    par32 ^= (pf5 & 16u) ? 0xFFFF0000u : 0u;
    par32 ^= (uint32_t)(0u - tp);
#pragma unroll
    for (int x = 0; x < 32; ++x) {
      if (x & (1 << j)) continue;
      const int x2 = x | (1 << j);
      const float se = ((par32 >> x) & 1u) ? ns : s;
      const float a0 = v[x], a1 = v[x2];
      v[x]  = c * a0 - se * a1;
      v[x2] = c * a1 + se * a0;
    }
  }
  if (R < 2) {
    uint32_t la = cumt ^ ((cumt >> 5) & 31u);
    lds[la] = v[0];
#pragma unroll
    for (int k = 1; k < 32; ++k) {
      const int j = __builtin_ctz((unsigned)k);
      const uint32_t m = pa.mm[5 * R + j];
      la ^= m ^ ((m >> 5) & 31u);
      lds[la] = v[k ^ (k >> 1)];
    }
  } else {
    uint32_t a = bb ^ cumt;
    state[a] = v[0];
#pragma unroll
    for (int k = 1; k < 32; ++k) {
      a ^= pa.mm[10 + __builtin_ctz((unsigned)k)];
      state[a] = v[k ^ (k >> 1)];
    }
  }
}

__global__ __launch_bounds__(1024, 4) void kpassB(float* __restrict__ state,
                                                  const float* __restrict__ trigRow,
                                                  PassArgsB pa)
{
  __shared__ float lds[32768];
  const uint32_t t = threadIdx.x;
  const uint32_t bb = (uint32_t)blockIdx.x << 15;
  const float4* g4 = (const float4*)(state + bb);
#pragma unroll
  for (int i = 0; i < 8; ++i) {
    float4 val = g4[t + i * 1024];
    uint32_t a = (t + (uint32_t)i * 1024u) * 4u;
    uint32_t s0 = a ^ ((a >> 5) & 31u);
    lds[s0 ^ 0u] = val.x; lds[s0 ^ 1u] = val.y; lds[s0 ^ 2u] = val.z; lds[s0 ^ 3u] = val.w;
  }
  __syncthreads();
  const float2* cs2 = (const float2*)trigRow;
  doRoundB<0>(lds, pa, cs2, bb, nullptr);
  __syncthreads();
  doRoundB<1>(lds, pa, cs2, bb, nullptr);
  __syncthreads();
  doRoundB<2>(lds, pa, cs2, bb, state);
}

// init: layer-0 product state computed analytically into LDS, then layer-1 passB.
__global__ __launch_bounds__(1024, 4) void kinit(float* __restrict__ state,
                                                 const float* __restrict__ trig,
                                                 PassArgsB pa)
{
  __shared__ float lds[32768];
  const uint32_t t = threadIdx.x;
  const uint32_t bb = (uint32_t)blockIdx.x << 15;
  const float2* cs0 = (const float2*)trig;      // layer 0, indexed by bit
  float tc[15], ts[15];
#pragma unroll
  for (int b = 0; b < 15; ++b) { float2 w = cs0[b]; tc[b] = w.x; ts[b] = w.y; }
  float ph = 1.0f;
#pragma unroll
  for (int b = 15; b < 25; ++b) { float2 w = cs0[b]; ph *= ((bb >> b) & 1u) ? w.y : w.x; }
  float pt = ph;
#pragma unroll
  for (int b = 2; b < 12; ++b) pt *= ((t >> (b - 2)) & 1u) ? ts[b] : tc[b];
  const float w00 = tc[0] * tc[1], w10 = ts[0] * tc[1], w01 = tc[0] * ts[1], w11 = ts[0] * ts[1];
#pragma unroll
  for (int i = 0; i < 8; ++i) {
    float pi = pt;
    pi *= (i & 1) ? ts[12] : tc[12];
    pi *= (i & 2) ? ts[13] : tc[13];
    pi *= (i & 4) ? ts[14] : tc[14];
    uint32_t a = (uint32_t)i * 4096u + t * 4u;
    uint32_t s0 = a ^ ((a >> 5) & 31u);
    lds[s0 ^ 0u] = pi * w00; lds[s0 ^ 1u] = pi * w10;
    lds[s0 ^ 2u] = pi * w01; lds[s0 ^ 3u] = pi * w11;
  }
  __syncthreads();
  const float2* cs1 = (const float2*)trig + 25; // layer 1
  doRoundB<0>(lds, pa, cs1, bb, nullptr);
  __syncthreads();
  doRoundB<1>(lds, pa, cs1, bb, nullptr);
  __syncthreads();
  doRoundB<2>(lds, pa, cs1, bb, state);
}

// ---------------- passA rounds (10 masks, pivots 15..24, no bits <5) -------
template<int R, bool FIN>
__device__ __forceinline__ void doRoundA(float* __restrict__ lds, const PassArgsA& pa,
                                         const float2* __restrict__ cs2, uint32_t sbase,
                                         float* __restrict__ state, uint32_t fz, uint32_t pfz,
                                         float* __restrict__ wsum)
{
  const uint32_t t = threadIdx.x;
  const uint32_t slo = t & 31u;
  const uint32_t yf  = t >> 5;
  uint32_t cumt = 0u;
#pragma unroll
  for (int k = 0; k < 5; ++k) {
    const int d = (R == 0) ? (5 + k) : k;
    cumt ^= ((yf >> k) & 1u) ? pa.mm[d] : 0u;
  }
  const uint32_t Ab = sbase ^ slo ^ cumt;
  const uint32_t labase = ((R == 0) ? (yf << 10) : (yf << 5)) + slo;
  float v[32];
  {
    uint32_t la = labase ^ ((labase >> 5) & 31u);
    v[0] = lds[la];
#pragma unroll
    for (int k = 1; k < 32; ++k) {
      const int j = __builtin_ctz((unsigned)k);
      la ^= (R == 0) ? ((1u << (5 + j)) | (1u << j)) : (1u << (10 + j));
      v[k ^ (k >> 1)] = lds[la];
    }
  }
#pragma unroll
  for (int j = 0; j < 5; ++j) {
    const int dim = 5 * R + j;
    const float2 w = cs2[dim];
    const float c = w.x, s = w.y, ns = -s;
    const uint32_t tp = __popc(Ab & pa.ff[dim]) & 1u;
    const uint32_t pf5 = (pa.pf[dim] >> (5 * R)) & 31u;
    uint32_t par32 = 0u;
    par32 ^= (pf5 & 1u)  ? 0xAAAAAAAAu : 0u;
    par32 ^= (pf5 & 2u)  ? 0xCCCCCCCCu : 0u;
    par32 ^= (pf5 & 4u)  ? 0xF0F0F0F0u : 0u;
    par32 ^= (pf5 & 8u)  ? 0xFF00FF00u : 0u;
    par32 ^= (pf5 & 16u) ? 0xFFFF0000u : 0u;
    par32 ^= (uint32_t)(0u - tp);
#pragma unroll
    for (int x = 0; x < 32; ++x) {
      if (x & (1 << j)) continue;
      const int x2 = x | (1 << j);
      const float se = ((par32 >> x) & 1u) ? ns : s;
      const float a0 = v[x], a1 = v[x2];
      v[x]  = c * a0 - se * a1;
      v[x2] = c * a1 + se * a0;
    }
  }
  if (R == 0) {
    uint32_t la = labase ^ ((labase >> 5) & 31u);
    lds[la] = v[0];
#pragma unroll
    for (int k = 1; k < 32; ++k) {
      const int j = __builtin_ctz((unsigned)k);
      la ^= (1u << (5 + j)) | (1u << j);
      lds[la] = v[k ^ (k >> 1)];
    }
  } else if (!FIN) {
    uint32_t a = Ab;
    state[a] = v[0];
#pragma unroll
    for (int k = 1; k < 32; ++k) {
      a ^= pa.mm[5 + __builtin_ctz((unsigned)k)];
      state[a] = v[k ^ (k >> 1)];
    }
  } else {
    float acc = 0.0f;
    const uint32_t tpz = __popc(Ab & fz) & 1u;
    const uint32_t pz5 = (pfz >> 5) & 31u;
    uint32_t par32 = 0u;
    par32 ^= (pz5 & 1u)  ? 0xAAAAAAAAu : 0u;
    par32 ^= (pz5 & 2u)  ? 0xCCCCCCCCu : 0u;
    par32 ^= (pz5 & 4u)  ? 0xF0F0F0F0u : 0u;
    par32 ^= (pz5 & 8u)  ? 0xFF00FF00u : 0u;
    par32 ^= (pz5 & 16u) ? 0xFFFF0000u : 0u;
    par32 ^= (uint32_t)(0u - tpz);
#pragma unroll
    for (int x = 0; x < 32; ++x) {
      const float q = v[x] * v[x];
      acc += ((par32 >> x) & 1u) ? -q : q;
    }
#pragma unroll
    for (int off = 32; off >= 1; off >>= 1) acc += __shfl_down(acc, off, 64);
    if ((t & 63u) == 0u) wsum[t >> 6] = acc;
  }
}

template<bool FIN>
__global__ __launch_bounds__(1024, 4) void kpassA(float* __restrict__ state,
                                                  const float* __restrict__ trigRow,
                                                  PassArgsA pa, uint32_t fz, uint32_t pfz,
                                                  float* __restrict__ outp)
{
  __shared__ float lds[32768];
  __shared__ float wsum[16];
  const uint32_t t = threadIdx.x;
  const uint32_t sbase = (uint32_t)blockIdx.x << 5;
  const uint32_t th = t >> 3;
  uint32_t cy = 0u;
#pragma unroll
  for (int k = 0; k < 7; ++k) cy ^= ((th >> k) & 1u) ? pa.mm[k] : 0u;
#pragma unroll
  for (int i = 0; i < 8; ++i) {
    if (i) cy ^= pa.mm[7 + __builtin_ctz((unsigned)i)];
    const uint32_t gi = (uint32_t)(i ^ (i >> 1));
    const uint32_t y = th | (gi << 7);
    const float4* p4 = (const float4*)(state + (sbase ^ cy));
    float4 val = p4[t & 7u];
    uint32_t la = (y << 5) + (t & 7u) * 4u;
    uint32_t s0 = la ^ ((la >> 5) & 31u);
    lds[s0 ^ 0u] = val.x; lds[s0 ^ 1u] = val.y; lds[s0 ^ 2u] = val.z; lds[s0 ^ 3u] = val.w;
  }
  __syncthreads();
  const float2* csA = (const float2*)trigRow + 15;
  doRoundA<0, false>(lds, pa, csA, sbase, nullptr, 0u, 0u, nullptr);
  __syncthreads();
  doRoundA<1, FIN>(lds, pa, csA, sbase, state, fz, pfz, wsum);
  if (FIN) {
    __syncthreads();
    if (t == 0) {
      double ssum = 0.0;
#pragma unroll
      for (int w = 0; w < 16; ++w) ssum += (double)wsum[w];
      atomicAdd(outp, (float)ssum);
    }
  }
}

extern "C" void kernel_launch(void* const* d_in, const int* in_sizes, int n_in,
                              void* d_out, int out_size, void* d_ws, size_t ws_size,
                              hipStream_t stream)
{
  (void)in_sizes; (void)n_in; (void)out_size; (void)ws_size;
  const float* theta = (const float*)d_in[0];
  float* outp  = (float*)d_out;
  float* state = (float*)d_ws;                               // 2^25 floats
  float* trig  = (float*)((char*)d_ws + (size_t)(1u << 25) * 4u); // 400 floats

  // ---- GF(2) bookkeeping: sigma columns / sigma^-1 rows per layer ----
  uint32_t col[25], inv[25];
  for (int j = 0; j < 25; ++j) { col[j] = 1u << j; inv[j] = 1u << j; }
  uint32_t M[8][25], F[8][25];
  for (int l = 0; l < 8; ++l) {
    for (int b = 0; b < 25; ++b) { M[l][b] = col[b]; F[l][b] = inv[b]; }
    for (int w = 0; w < 24; ++w) {          // CNOT chain of layer l
      const int cb = 24 - w, tb = 23 - w;   // control bit, target bit
      col[cb] ^= col[tb];
      inv[tb] ^= inv[cb];
    }
  }
  const uint32_t fz = inv[24];              // final Z-sign functional

  auto par1 = [](uint32_t x) -> uint32_t { return (uint32_t)__builtin_popcount(x) & 1u; };

  PassArgsB bargs[8];
  PassArgsA aargs[8];
  for (int l = 1; l < 8; ++l) {
    for (int j = 0; j < 15; ++j) {
      bargs[l].mm[j] = M[l][j]; bargs[l].ff[j] = F[l][j];
      uint32_t p = 0;
      for (int i = 0; i < 15; ++i) p |= par1(M[l][i] & F[l][j]) << i;
      bargs[l].pf[j] = p;
    }
    for (int j = 0; j < 10; ++j) {
      aargs[l].mm[j] = M[l][15 + j]; aargs[l].ff[j] = F[l][15 + j];
      uint32_t p = 0;
      for (int i = 0; i < 10; ++i) p |= par1(M[l][15 + i] & F[l][15 + j]) << i;
      aargs[l].pf[j] = p;
    }
  }
  uint32_t pfz = 0;
  for (int i = 0; i < 10; ++i) pfz |= par1(M[7][15 + i] & fz) << i;

  kprep<<<1, 256, 0, stream>>>(theta, trig, outp);
  kinit<<<1024, 1024, 0, stream>>>(state, trig, bargs[1]);
  kpassA<false><<<1024, 1024, 0, stream>>>(state, trig + 50, aargs[1], fz, pfz, outp);
  for (int l = 2; l < 7; ++l) {
    kpassB<<<1024, 1024, 0, stream>>>(state, trig + 50 * l, bargs[l]);
    kpassA<false><<<1024, 1024, 0, stream>>>(state, trig + 50 * l, aargs[l], fz, pfz, outp);
  }
  kpassB<<<1024, 1024, 0, stream>>>(state, trig + 50 * 7, bargs[7]);
  kpassA<true><<<1024, 1024, 0, stream>>>(state, trig + 50 * 7, aargs[7], fz, pfz, outp);
}

// Round 2
// 842.580 us; speedup vs baseline: 1.2085x; 1.2085x over previous
//
#include <hip/hip_runtime.h>
#include <stdint.h>

// 25-qubit, 8-layer RY + CNOT-chain circuit, output <Z_q0>.
// CNOT chains are deferred into a GF(2) change-of-basis; only the 200 RYs
// touch the 2^25-float state. Masks are circuit-structure-only -> constexpr,
// kernels templated on layer. Key identity: F rows are the dual basis of M
// columns (f_j . m_i = delta_ij), so per-pair sign patterns collapse to one
// sign bit per dim per thread: se = popc(high_part & f_dim) ? -s : s.
// Per layer: kpassB (pivots 0..14, contiguous 2^15-float tile, 3 register
// rounds of 5 dims, LDS 128 KiB slot-permuted swizzle, b128 staging) and
// kpassA (pivots 15..24, combo gathers, 2 register rounds). State = 2^25 f32
// in d_ws (128 MiB, L3-resident).

#define NQ 25
#define DEPTH 8

struct MaskSet {
  uint32_t M[DEPTH][NQ];   // M[l][b] = column b of W_l (pairing masks)
  uint32_t F[DEPTH][NQ];   // F[l][b] = row b of W_l^-1 (orientation functionals)
  uint32_t fz;             // final Z functional (row 24 of W_8^-1)
};

__host__ __device__ constexpr MaskSet buildMasks() {
  MaskSet r{};
  uint32_t col[NQ] = {}, inv[NQ] = {};
  for (int j = 0; j < NQ; ++j) { col[j] = 1u << j; inv[j] = 1u << j; }
  for (int l = 0; l < DEPTH; ++l) {
    for (int b = 0; b < NQ; ++b) { r.M[l][b] = col[b]; r.F[l][b] = inv[b]; }
    for (int w = 0; w < NQ - 1; ++w) {   // CNOT chain of layer l
      const int cb = 24 - w, tb = 23 - w;
      col[cb] ^= col[tb];
      inv[tb] ^= inv[cb];
    }
  }
  r.fz = inv[24];
  return r;
}

constexpr MaskSet MK = buildMasks();

// Swizzle: XOR low slot bits (2..4) with owner bits (5..7). Linear over GF(2),
// keeps 16B alignment -> b128-friendly, conflict-free for both segment-major
// (b128) and low-5-bijective (b32) access patterns.
__host__ __device__ constexpr uint32_t cswz(uint32_t a) { return a ^ ((a >> 3) & 28u); }

__host__ __device__ constexpr uint32_t kxorB(int L, int d0, uint32_t y) {
  uint32_t a = 0;
  for (int i = 0; i < 5; ++i) if ((y >> i) & 1u) a ^= MK.M[L][d0 + i];
  return a;
}

__host__ __device__ constexpr uint32_t cpar(uint32_t x) {
  uint32_t p = 0;
  for (int i = 0; i < 32; ++i) p ^= (x >> i) & 1u;
  return p;
}

__global__ void kprep(const float* __restrict__ theta, float* __restrict__ trig,
                      float* __restrict__ outp)
{
  int t = threadIdx.x;
  if (t == 0) outp[0] = 0.0f;
  if (t < 200) {
    int l = t / 25, b = t % 25;            // b = bit position, qubit w = 24-b
    float th = theta[l * 25 + (24 - b)] * 0.5f;
    trig[2 * t]     = cosf(th);
    trig[2 * t + 1] = sinf(th);
  }
}

// ---- passB tail: R0 (dims 0..4, v in address order) -> LDS -> R1 -> R2 -> store
template<int L>
__device__ __forceinline__ void passB_tail(float (&v)[32], float* lds,
                                           const uint32_t t, const uint32_t bb,
                                           const float* __restrict__ trig,
                                           float* __restrict__ state)
{
  const float2* cs = (const float2*)(trig + 50 * L);
  // R0: dims 0..4. Element o <-> address bb|(t<<5)|o. Pair o <-> o^mu_j,
  // base = even parity of (o & f_j); its orientation bit = popc(high & f_j).
#pragma unroll
  for (int j = 0; j < 5; ++j) {
    const float2 w = cs[j];
    const float c = w.x, s = w.y;
    const uint32_t mu = MK.M[L][j];            // within bits 0..4
    const uint32_t fj = MK.F[L][j];
    const float se = (__builtin_popcount((bb | (t << 5)) & fj) & 1) ? -s : s;
#pragma unroll
    for (uint32_t o = 0; o < 32; ++o) {
      if (__builtin_popcount(o & fj & 31u) & 1) continue;   // compile-time
      const uint32_t o2 = o ^ mu;
      const float a0 = v[o], a1 = v[o2];
      v[o]  = c * a0 - se * a1;
      v[o2] = c * a1 + se * a0;
    }
  }
  // write own segment to LDS (layout: lds[cswz(linear addr)])
  {
    float4* l4 = (float4*)lds;
#pragma unroll
    for (uint32_t k = 0; k < 8; ++k) {
      float4 q = { v[4*k], v[4*k+1], v[4*k+2], v[4*k+3] };
      l4[cswz((t << 5) + 4u * k) >> 2] = q;
    }
  }
  __syncthreads();
  // R1: dims 5..9; thread coords: dims 0..4 <- t bits 0..4, dims 10..14 <- t bits 5..9
  uint32_t B1 = 0u;
#pragma unroll
  for (int i = 0; i < 5; ++i) B1 ^= ((t >> i) & 1u) ? MK.M[L][i] : 0u;
#pragma unroll
  for (int i = 0; i < 5; ++i) B1 ^= ((t >> (5 + i)) & 1u) ? MK.M[L][10 + i] : 0u;
  const uint32_t B1s = cswz(B1);
#pragma unroll
  for (uint32_t y = 0; y < 32; ++y) v[y] = lds[B1s ^ cswz(kxorB(L, 5, y))];
#pragma unroll
  for (int j = 0; j < 5; ++j) {
    const float2 w = cs[5 + j];
    const float c = w.x, s = w.y;
    const float se = (__builtin_popcount(bb & MK.F[L][5 + j]) & 1) ? -s : s;
#pragma unroll
    for (uint32_t y = 0; y < 32; ++y) {
      if ((y >> j) & 1u) continue;
      const uint32_t y2 = y | (1u << j);
      const float a0 = v[y], a1 = v[y2];
      v[y]  = c * a0 - se * a1;
      v[y2] = c * a1 + se * a0;
    }
  }
#pragma unroll
  for (uint32_t y = 0; y < 32; ++y) lds[B1s ^ cswz(kxorB(L, 5, y))] = v[y];
  __syncthreads();
  // R2: dims 10..14; thread coords: dims 0..4 <- t bits 0..4, dims 5..9 <- t bits 5..9
  uint32_t B2 = 0u;
#pragma unroll
  for (int i = 0; i < 5; ++i) B2 ^= ((t >> i) & 1u) ? MK.M[L][i] : 0u;
#pragma unroll
  for (int i = 0; i < 5; ++i) B2 ^= ((t >> (5 + i)) & 1u) ? MK.M[L][5 + i] : 0u;
  const uint32_t B2s = cswz(B2);
#pragma unroll
  for (uint32_t y = 0; y < 32; ++y) v[y] = lds[B2s ^ cswz(kxorB(L, 10, y))];
#pragma unroll
  for (int j = 0; j < 5; ++j) {
    const float2 w = cs[10 + j];
    const float c = w.x, s = w.y;
    const float se = (__builtin_popcount(bb & MK.F[L][10 + j]) & 1) ? -s : s;
#pragma unroll
    for (uint32_t y = 0; y < 32; ++y) {
      if ((y >> j) & 1u) continue;
      const uint32_t y2 = y | (1u << j);
      const float a0 = v[y], a1 = v[y2];
      v[y]  = c * a0 - se * a1;
      v[y2] = c * a1 + se * a0;
    }
  }
  // store: per inst, lanes 0..31 cover one 128B segment, lanes 32..63 another
#pragma unroll
  for (uint32_t y = 0; y < 32; ++y) state[bb ^ B2 ^ kxorB(L, 10, y)] = v[y];
}

template<int L>
__global__ __launch_bounds__(1024, 4) void kpassB(float* __restrict__ state,
                                                  const float* __restrict__ trig)
{
  __shared__ __align__(16) float lds[32768];
  const uint32_t t = threadIdx.x;
  const uint32_t bb = (uint32_t)blockIdx.x << 15;
  // staging: coalesced global float4 -> LDS b128 (cswz layout)
  {
    const float4* g4 = (const float4*)(state + bb);
    float4* l4 = (float4*)lds;
#pragma unroll
    for (uint32_t i = 0; i < 8; ++i) {
      float4 q = g4[i * 1024u + t];
      l4[cswz((i * 1024u + t) << 2) >> 2] = q;
    }
  }
  __syncthreads();
  float v[32];
  {
    const float4* l4 = (const float4*)lds;
#pragma unroll
    for (uint32_t k = 0; k < 8; ++k) {
      float4 q = l4[cswz((t << 5) + 4u * k) >> 2];
      v[4*k] = q.x; v[4*k+1] = q.y; v[4*k+2] = q.z; v[4*k+3] = q.w;
    }
  }
  passB_tail<L>(v, lds, t, bb, trig, state);
}

// kinit: layer-0 product state built analytically in address order (62 mults),
// then layer-1 passB tail.
__global__ __launch_bounds__(1024, 4) void kinit(float* __restrict__ state,
                                                 const float* __restrict__ trig)
{
  __shared__ __align__(16) float lds[32768];
  const uint32_t t = threadIdx.x;
  const uint32_t bb = (uint32_t)blockIdx.x << 15;
  const float2* cs0 = (const float2*)trig;       // layer 0, indexed by bit
  const uint32_t hi = bb | (t << 5);
  float pt = 1.0f;
#pragma unroll
  for (int b = 5; b < 25; ++b) {
    const float2 w = cs0[b];
    pt *= ((hi >> b) & 1u) ? w.y : w.x;
  }
  float v[32];
  v[0] = pt;
#pragma unroll
  for (int j = 0; j < 5; ++j) {
    const float2 w = cs0[j];
#pragma unroll
    for (int o = 0; o < (1 << j); ++o) {
      v[o | (1 << j)] = v[o] * w.y;
      v[o]            = v[o] * w.x;
    }
  }
  passB_tail<1>(v, lds, t, bb, trig, state);
}

// ---- passA: pivots 15..24. Block = 32 contiguous spectators x 1024 combos.
// All orientation signs vanish (delta identity + footprint), except the final
// Z-functional pattern in FIN.
template<int L, bool FIN>
__global__ __launch_bounds__(1024, 4) void kpassA(float* __restrict__ state,
                                                  const float* __restrict__ trig,
                                                  float* __restrict__ outp)
{
  __shared__ __align__(16) float lds[32768];
  __shared__ float wsum[16];
  const uint32_t t = threadIdx.x;
  const uint32_t sbase = (uint32_t)blockIdx.x << 5;
  const float2* cs = (const float2*)(trig + 50 * L) + 15;
  {
    const uint32_t th = t >> 3;
    uint32_t cy = 0u;
#pragma unroll
    for (int k = 0; k < 7; ++k) cy ^= ((th >> k) & 1u) ? MK.M[L][15 + k] : 0u;
#pragma unroll
    for (uint32_t i = 0; i < 8; ++i) {
      if (i) cy ^= MK.M[L][22 + __builtin_ctz(i)];
      const uint32_t gi = i ^ (i >> 1);
      const uint32_t y = th | (gi << 7);
      const float4* p4 = (const float4*)(state + (sbase ^ cy));
      const float4 val = p4[t & 7u];
      const uint32_t la = (y << 5) + ((t & 7u) << 2);
      const uint32_t s0 = la ^ ((la >> 5) & 31u);
      lds[s0 ^ 0u] = val.x; lds[s0 ^ 1u] = val.y;
      lds[s0 ^ 2u] = val.z; lds[s0 ^ 3u] = val.w;
    }
  }
  __syncthreads();
  const uint32_t slo = t & 31u;
  const uint32_t yf  = t >> 5;
  float v[32];
  // R0: register dims 0..4 (pivots 15..19); yf -> dims 5..9
  {
    const uint32_t labase = (yf << 10) + slo;
    uint32_t la = labase ^ ((labase >> 5) & 31u);
    v[0] = lds[la];
#pragma unroll
    for (int k = 1; k < 32; ++k) {
      const int j = __builtin_ctz((unsigned)k);
      la ^= (1u << (5 + j)) | (1u << j);     // toggle y-bit j + swizzle comp
      v[k ^ (k >> 1)] = lds[la];
    }
  }
#pragma unroll
  for (int j = 0; j < 5; ++j) {
    const float2 w = cs[j];
    const float c = w.x, s = w.y;
#pragma unroll
    for (uint32_t x = 0; x < 32; ++x) {
      if ((x >> j) & 1u) continue;
      const uint32_t x2 = x | (1u << j);
      const float a0 = v[x], a1 = v[x2];
      v[x]  = c * a0 - s * a1;
      v[x2] = s * a0 + c * a1;
    }
  }
  {
    const uint32_t labase = (yf << 10) + slo;
    uint32_t la = labase ^ ((labase >> 5) & 31u);
    lds[la] = v[0];
#pragma unroll
    for (int k = 1; k < 32; ++k) {
      const int j = __builtin_ctz((unsigned)k);
      la ^= (1u << (5 + j)) | (1u << j);
      lds[la] = v[k ^ (k >> 1)];
    }
  }
  __syncthreads();
  // R1: register dims 5..9 (pivots 20..24); yf -> dims 0..4
  uint32_t cumt = 0u;
#pragma unroll
  for (int k = 0; k < 5; ++k) cumt ^= ((yf >> k) & 1u) ? MK.M[L][15 + k] : 0u;
  const uint32_t Ab = sbase ^ slo ^ cumt;
  {
    const uint32_t labase = (yf << 5) + slo;
    uint32_t la = labase ^ ((labase >> 5) & 31u);
    v[0] = lds[la];
#pragma unroll
    for (int k = 1; k < 32; ++k) {
      la ^= 1u << (10 + __builtin_ctz((unsigned)k));
      v[k ^ (k >> 1)] = lds[la];
    }
  }
#pragma unroll
  for (int j = 0; j < 5; ++j) {
    const float2 w = cs[5 + j];
    const float c = w.x, s = w.y;
#pragma unroll
    for (uint32_t x = 0; x < 32; ++x) {
      if ((x >> j) & 1u) continue;
      const uint32_t x2 = x | (1u << j);
      const float a0 = v[x], a1 = v[x2];
      v[x]  = c * a0 - s * a1;
      v[x2] = s * a0 + c * a1;
    }
  }
  if (!FIN) {
    uint32_t a = Ab;
    state[a] = v[0];
#pragma unroll
    for (int k = 1; k < 32; ++k) {
      a ^= MK.M[L][20 + __builtin_ctz((unsigned)k)];
      state[a] = v[k ^ (k >> 1)];
    }
  } else {
    constexpr uint32_t pz =
        (cpar(MK.M[L][20] & MK.fz) << 0) | (cpar(MK.M[L][21] & MK.fz) << 1) |
        (cpar(MK.M[L][22] & MK.fz) << 2) | (cpar(MK.M[L][23] & MK.fz) << 3) |
        (cpar(MK.M[L][24] & MK.fz) << 4);
    float acc = 0.0f;
#pragma unroll
    for (uint32_t x = 0; x < 32; ++x) {
      const float q = v[x] * v[x];
      acc += cpar(x & pz) ? -q : q;
    }
    if (__builtin_popcount(Ab & MK.fz) & 1) acc = -acc;
#pragma unroll
    for (int off = 32; off >= 1; off >>= 1) acc += __shfl_down(acc, off, 64);
    if ((t & 63u) == 0u) wsum[t >> 6] = acc;
    __syncthreads();
    if (t == 0) {
      float ssum = 0.0f;
#pragma unroll
      for (int w2 = 0; w2 < 16; ++w2) ssum += wsum[w2];
      atomicAdd(outp, ssum);
    }
  }
}

extern "C" void kernel_launch(void* const* d_in, const int* in_sizes, int n_in,
                              void* d_out, int out_size, void* d_ws, size_t ws_size,
                              hipStream_t stream)
{
  (void)in_sizes; (void)n_in; (void)out_size; (void)ws_size;
  const float* theta = (const float*)d_in[0];
  float* outp  = (float*)d_out;
  float* state = (float*)d_ws;                                    // 2^25 floats
  float* trig  = (float*)((char*)d_ws + (size_t)(1u << 25) * 4u); // 400 floats

  kprep<<<1, 256, 0, stream>>>(theta, trig, outp);
  kinit<<<1024, 1024, 0, stream>>>(state, trig);
  kpassA<1, false><<<1024, 1024, 0, stream>>>(state, trig, outp);
  kpassB<2><<<1024, 1024, 0, stream>>>(state, trig);
  kpassA<2, false><<<1024, 1024, 0, stream>>>(state, trig, outp);
  kpassB<3><<<1024, 1024, 0, stream>>>(state, trig);
  kpassA<3, false><<<1024, 1024, 0, stream>>>(state, trig, outp);
  kpassB<4><<<1024, 1024, 0, stream>>>(state, trig);
  kpassA<4, false><<<1024, 1024, 0, stream>>>(state, trig, outp);
  kpassB<5><<<1024, 1024, 0, stream>>>(state, trig);
  kpassA<5, false><<<1024, 1024, 0, stream>>>(state, trig, outp);
  kpassB<6><<<1024, 1024, 0, stream>>>(state, trig);
  kpassA<6, false><<<1024, 1024, 0, stream>>>(state, trig, outp);
  kpassB<7><<<1024, 1024, 0, stream>>>(state, trig);
  kpassA<7, true><<<1024, 1024, 0, stream>>>(state, trig, outp);
}

// Round 3
// 783.347 us; speedup vs baseline: 1.2999x; 1.0756x over previous
//
#include <hip/hip_runtime.h>
#include <stdint.h>

// 25-qubit, 8-layer RY + CNOT-chain circuit, output <Z_q0>.
// CNOT chains deferred into a GF(2) change-of-basis; only 200 RYs touch the
// 2^25-float state (d_ws, 128 MiB, L3-resident). Masks constexpr; kernels
// templated on layer. Dual-basis identity (F_j . M_i = delta_ij) collapses
// all per-pair sign patterns to one sign bit per dim per thread.
// Round 3: staging LDS round-trips removed — both passes load their R0
// fragments DIRECTLY global->registers (coalesced), so each pass has only
// its repartition exchanges in LDS (B: 2 exchanges, A: 1) and one fewer
// barrier, letting waves overlap load latency with R0 compute.

#define NQ 25
#define DEPTH 8

struct MaskSet {
  uint32_t M[DEPTH][NQ];   // M[l][b] = column b of W_l (pairing masks)
  uint32_t F[DEPTH][NQ];   // F[l][b] = row b of W_l^-1 (orientation functionals)
  uint32_t fz;             // final Z functional (row 24 of W_8^-1)
};

__host__ __device__ constexpr MaskSet buildMasks() {
  MaskSet r{};
  uint32_t col[NQ] = {}, inv[NQ] = {};
  for (int j = 0; j < NQ; ++j) { col[j] = 1u << j; inv[j] = 1u << j; }
  for (int l = 0; l < DEPTH; ++l) {
    for (int b = 0; b < NQ; ++b) { r.M[l][b] = col[b]; r.F[l][b] = inv[b]; }
    for (int w = 0; w < NQ - 1; ++w) {   // CNOT chain of layer l
      const int cb = 24 - w, tb = 23 - w;
      col[cb] ^= col[tb];
      inv[tb] ^= inv[cb];
    }
  }
  r.fz = inv[24];
  return r;
}

constexpr MaskSet MK = buildMasks();

// Swizzle: XOR low slot bits (2..4) with owner bits (5..7). Linear over GF(2),
// 16B-aligned groups preserved -> b128-friendly, conflict-free for both
// segment-major (b128) and low-5-bijective (b32) patterns.
__host__ __device__ constexpr uint32_t cswz(uint32_t a) { return a ^ ((a >> 3) & 28u); }

__host__ __device__ constexpr uint32_t kxorB(int L, int d0, uint32_t y) {
  uint32_t a = 0;
  for (int i = 0; i < 5; ++i) if ((y >> i) & 1u) a ^= MK.M[L][d0 + i];
  return a;
}

__host__ __device__ constexpr uint32_t cpar(uint32_t x) {
  uint32_t p = 0;
  for (int i = 0; i < 32; ++i) p ^= (x >> i) & 1u;
  return p;
}

__global__ void kprep(const float* __restrict__ theta, float* __restrict__ trig,
                      float* __restrict__ outp)
{
  int t = threadIdx.x;
  if (t == 0) outp[0] = 0.0f;
  if (t < 200) {
    int l = t / 25, b = t % 25;            // b = bit position, qubit w = 24-b
    float th = theta[l * 25 + (24 - b)] * 0.5f;
    trig[2 * t]     = cosf(th);
    trig[2 * t + 1] = sinf(th);
  }
}

// ---- passB tail: R0 (dims 0..4, v in tile-address order) -> LDS -> R1 ->
//      LDS -> R2 -> direct global store.
template<int L>
__device__ __forceinline__ void passB_tail(float (&v)[32], float* lds,
                                           const uint32_t t, const uint32_t bb,
                                           const float* __restrict__ trig,
                                           float* __restrict__ state)
{
  const float2* cs = (const float2*)(trig + 50 * L);
  // R0: dims 0..4. Element o <-> address bb|(t<<5)|o. Pair o <-> o^mu_j,
  // base element has even parity of (addr & f_j).
#pragma unroll
  for (int j = 0; j < 5; ++j) {
    const float2 w = cs[j];
    const float c = w.x, s = w.y;
    const uint32_t mu = MK.M[L][j];            // within bits 0..4
    const uint32_t fj = MK.F[L][j];
    const float se = (__builtin_popcount((bb | (t << 5)) & fj) & 1) ? -s : s;
#pragma unroll
    for (uint32_t o = 0; o < 32; ++o) {
      if (__builtin_popcount(o & fj & 31u) & 1) continue;   // compile-time
      const uint32_t o2 = o ^ mu;
      const float a0 = v[o], a1 = v[o2];
      v[o]  = c * a0 - se * a1;
      v[o2] = c * a1 + se * a0;
    }
  }
  // exchange 1: write own segment (b128, cswz layout)
  {
    float4* l4 = (float4*)lds;
#pragma unroll
    for (uint32_t k = 0; k < 8; ++k) {
      float4 q = { v[4*k], v[4*k+1], v[4*k+2], v[4*k+3] };
      l4[cswz((t << 5) + 4u * k) >> 2] = q;
    }
  }
  __syncthreads();
  // R1: dims 5..9; thread coords: dims 0..4 <- t bits 0..4, dims 10..14 <- t bits 5..9
  uint32_t B1 = 0u;
#pragma unroll
  for (int i = 0; i < 5; ++i) B1 ^= ((t >> i) & 1u) ? MK.M[L][i] : 0u;
#pragma unroll
  for (int i = 0; i < 5; ++i) B1 ^= ((t >> (5 + i)) & 1u) ? MK.M[L][10 + i] : 0u;
  const uint32_t B1s = cswz(B1);
#pragma unroll
  for (uint32_t y = 0; y < 32; ++y) v[y] = lds[B1s ^ cswz(kxorB(L, 5, y))];
#pragma unroll
  for (int j = 0; j < 5; ++j) {
    const float2 w = cs[5 + j];
    const float c = w.x, s = w.y;
    const float se = (__builtin_popcount(bb & MK.F[L][5 + j]) & 1) ? -s : s;
#pragma unroll
    for (uint32_t y = 0; y < 32; ++y) {
      if ((y >> j) & 1u) continue;
      const uint32_t y2 = y | (1u << j);
      const float a0 = v[y], a1 = v[y2];
      v[y]  = c * a0 - se * a1;
      v[y2] = c * a1 + se * a0;
    }
  }
  __syncthreads();   // protect re-write of same slots
#pragma unroll
  for (uint32_t y = 0; y < 32; ++y) lds[B1s ^ cswz(kxorB(L, 5, y))] = v[y];
  __syncthreads();
  // R2: dims 10..14; thread coords: dims 0..4 <- t bits 0..4, dims 5..9 <- t bits 5..9
  uint32_t B2 = 0u;
#pragma unroll
  for (int i = 0; i < 5; ++i) B2 ^= ((t >> i) & 1u) ? MK.M[L][i] : 0u;
#pragma unroll
  for (int i = 0; i < 5; ++i) B2 ^= ((t >> (5 + i)) & 1u) ? MK.M[L][5 + i] : 0u;
  const uint32_t B2s = cswz(B2);
#pragma unroll
  for (uint32_t y = 0; y < 32; ++y) v[y] = lds[B2s ^ cswz(kxorB(L, 10, y))];
#pragma unroll
  for (int j = 0; j < 5; ++j) {
    const float2 w = cs[10 + j];
    const float c = w.x, s = w.y;
    const float se = (__builtin_popcount(bb & MK.F[L][10 + j]) & 1) ? -s : s;
#pragma unroll
    for (uint32_t y = 0; y < 32; ++y) {
      if ((y >> j) & 1u) continue;
      const uint32_t y2 = y | (1u << j);
      const float a0 = v[y], a1 = v[y2];
      v[y]  = c * a0 - se * a1;
      v[y2] = c * a1 + se * a0;
    }
  }
  // direct store: per inst, each 32-lane phase covers one 128B segment
#pragma unroll
  for (uint32_t y = 0; y < 32; ++y) state[bb ^ B2 ^ kxorB(L, 10, y)] = v[y];
}

template<int L>
__global__ __launch_bounds__(1024, 4) void kpassB(float* __restrict__ state,
                                                  const float* __restrict__ trig)
{
  __shared__ __align__(16) float lds[32768];
  const uint32_t t = threadIdx.x;
  const uint32_t bb = (uint32_t)blockIdx.x << 15;
  // direct load: thread t owns 128 contiguous bytes (tile-address order)
  float v[32];
  {
    const float4* g4 = (const float4*)(state + bb + (t << 5));
#pragma unroll
    for (uint32_t k = 0; k < 8; ++k) {
      float4 q = g4[k];
      v[4*k] = q.x; v[4*k+1] = q.y; v[4*k+2] = q.z; v[4*k+3] = q.w;
    }
  }
  passB_tail<L>(v, lds, t, bb, trig, state);
}

// kinit: layer-0 product state built analytically in tile-address order
// (62 mults), then layer-1 passB tail. Write-only pass.
__global__ __launch_bounds__(1024, 4) void kinit(float* __restrict__ state,
                                                 const float* __restrict__ trig)
{
  __shared__ __align__(16) float lds[32768];
  const uint32_t t = threadIdx.x;
  const uint32_t bb = (uint32_t)blockIdx.x << 15;
  const float2* cs0 = (const float2*)trig;       // layer 0, indexed by bit
  const uint32_t hi = bb | (t << 5);
  float pt = 1.0f;
#pragma unroll
  for (int b = 5; b < 25; ++b) {
    const float2 w = cs0[b];
    pt *= ((hi >> b) & 1u) ? w.y : w.x;
  }
  float v[32];
  v[0] = pt;
#pragma unroll
  for (int j = 0; j < 5; ++j) {
    const float2 w = cs0[j];
#pragma unroll
    for (int o = 0; o < (1 << j); ++o) {
      v[o | (1 << j)] = v[o] * w.y;
      v[o]            = v[o] * w.x;
    }
  }
  passB_tail<1>(v, lds, t, bb, trig, state);
}

// ---- passA: pivots 15..24. Block = 32 contiguous spectators (slo) x 1024
// combos. Direct b32 loads (lanes 0..31 = one 128B segment), one LDS
// exchange, direct stores. All orientation signs vanish: F[L][15+j] lives in
// bits >=15, spectator/base bits <=14, combo terms give the delta identity.
template<int L, bool FIN>
__global__ __launch_bounds__(1024, 4) void kpassA(float* __restrict__ state,
                                                  const float* __restrict__ trig,
                                                  float* __restrict__ outp)
{
  __shared__ __align__(16) float lds[32768];
  __shared__ float wsum[16];
  const uint32_t t = threadIdx.x;
  const uint32_t sbase = (uint32_t)blockIdx.x << 5;   // bits 5..14
  const float2* cs = (const float2*)(trig + 50 * L) + 15;
  const uint32_t slo = t & 31u;
  const uint32_t yf  = t >> 5;
  // R0: register dims = pivots 15..19; yf -> pivots 20..24.
  uint32_t cy = 0u;
#pragma unroll
  for (int k = 0; k < 5; ++k) cy ^= ((yf >> k) & 1u) ? MK.M[L][20 + k] : 0u;
  const uint32_t A0 = sbase ^ slo ^ cy;
  float v[32];
#pragma unroll
  for (uint32_t x = 0; x < 32; ++x) v[x] = state[A0 ^ kxorB(L, 15, x)];
#pragma unroll
  for (int j = 0; j < 5; ++j) {
    const float2 w = cs[j];
    const float c = w.x, s = w.y;
#pragma unroll
    for (uint32_t x = 0; x < 32; ++x) {
      if ((x >> j) & 1u) continue;
      const uint32_t x2 = x | (1u << j);
      const float a0 = v[x], a1 = v[x2];
      v[x]  = c * a0 - s * a1;
      v[x2] = s * a0 + c * a1;
    }
  }
  // exchange: slot = (yf<<10)|(x<<5)|slo, swizzled (low5 ^= bits 5..9)
#pragma unroll
  for (uint32_t x = 0; x < 32; ++x) {
    const uint32_t la = (yf << 10) + (x << 5) + slo;
    lds[la ^ ((la >> 5) & 31u)] = v[x];
  }
  __syncthreads();
  // R1: register dims = pivots 20..24; yf -> pivots 15..19.
  uint32_t cumt = 0u;
#pragma unroll
  for (int k = 0; k < 5; ++k) cumt ^= ((yf >> k) & 1u) ? MK.M[L][15 + k] : 0u;
  const uint32_t Ab = sbase ^ slo ^ cumt;
  {
    const uint32_t labase = (yf << 5) + slo;
    uint32_t la = labase ^ ((labase >> 5) & 31u);
    v[0] = lds[la];
#pragma unroll
    for (int k = 1; k < 32; ++k) {
      la ^= 1u << (10 + __builtin_ctz((unsigned)k));
      v[k ^ (k >> 1)] = lds[la];
    }
  }
#pragma unroll
  for (int j = 0; j < 5; ++j) {
    const float2 w = cs[5 + j];
    const float c = w.x, s = w.y;
#pragma unroll
    for (uint32_t x = 0; x < 32; ++x) {
      if ((x >> j) & 1u) continue;
      const uint32_t x2 = x | (1u << j);
      const float a0 = v[x], a1 = v[x2];
      v[x]  = c * a0 - s * a1;
      v[x2] = s * a0 + c * a1;
    }
  }
  if (!FIN) {
    uint32_t a = Ab;
    state[a] = v[0];
#pragma unroll
    for (int k = 1; k < 32; ++k) {
      a ^= MK.M[L][20 + __builtin_ctz((unsigned)k)];
      state[a] = v[k ^ (k >> 1)];
    }
  } else {
    constexpr uint32_t pz =
        (cpar(MK.M[L][20] & MK.fz) << 0) | (cpar(MK.M[L][21] & MK.fz) << 1) |
        (cpar(MK.M[L][22] & MK.fz) << 2) | (cpar(MK.M[L][23] & MK.fz) << 3) |
        (cpar(MK.M[L][24] & MK.fz) << 4);
    float acc = 0.0f;
#pragma unroll
    for (uint32_t x = 0; x < 32; ++x) {
      const float q = v[x] * v[x];
      acc += cpar(x & pz) ? -q : q;
    }
    if (__builtin_popcount(Ab & MK.fz) & 1) acc = -acc;
#pragma unroll
    for (int off = 32; off >= 1; off >>= 1) acc += __shfl_down(acc, off, 64);
    if ((t & 63u) == 0u) wsum[t >> 6] = acc;
    __syncthreads();
    if (t == 0) {
      float ssum = 0.0f;
#pragma unroll
      for (int w2 = 0; w2 < 16; ++w2) ssum += wsum[w2];
      atomicAdd(outp, ssum);
    }
  }
}

extern "C" void kernel_launch(void* const* d_in, const int* in_sizes, int n_in,
                              void* d_out, int out_size, void* d_ws, size_t ws_size,
                              hipStream_t stream)
{
  (void)in_sizes; (void)n_in; (void)out_size; (void)ws_size;
  const float* theta = (const float*)d_in[0];
  float* outp  = (float*)d_out;
  float* state = (float*)d_ws;                                    // 2^25 floats
  float* trig  = (float*)((char*)d_ws + (size_t)(1u << 25) * 4u); // 400 floats

  kprep<<<1, 256, 0, stream>>>(theta, trig, outp);
  kinit<<<1024, 1024, 0, stream>>>(state, trig);
  kpassA<1, false><<<1024, 1024, 0, stream>>>(state, trig, outp);
  kpassB<2><<<1024, 1024, 0, stream>>>(state, trig);
  kpassA<2, false><<<1024, 1024, 0, stream>>>(state, trig, outp);
  kpassB<3><<<1024, 1024, 0, stream>>>(state, trig);
  kpassA<3, false><<<1024, 1024, 0, stream>>>(state, trig, outp);
  kpassB<4><<<1024, 1024, 0, stream>>>(state, trig);
  kpassA<4, false><<<1024, 1024, 0, stream>>>(state, trig, outp);
  kpassB<5><<<1024, 1024, 0, stream>>>(state, trig);
  kpassA<5, false><<<1024, 1024, 0, stream>>>(state, trig, outp);
  kpassB<6><<<1024, 1024, 0, stream>>>(state, trig);
  kpassA<6, false><<<1024, 1024, 0, stream>>>(state, trig, outp);
  kpassB<7><<<1024, 1024, 0, stream>>>(state, trig);
  kpassA<7, true><<<1024, 1024, 0, stream>>>(state, trig, outp);
}